// Round 1
// baseline (4926.897 us; speedup 1.0000x reference)
//
#include <hip/hip_runtime.h>
#include <math.h>

#define B_   256
#define S_   160
#define V_   50000
#define E_   300
#define H_   256
#define T_   200
#define G4H  1024
#define CH   16
#define NCH  10

__device__ __forceinline__ float sigf(float x) {
    float e = expf(-fabsf(x));
    float p = 1.0f / (1.0f + e);
    return x >= 0.0f ? p : e * p;
}

// ---------------------------------------------------------------------------
// G[rnn, sl, b, n] = sum_e emb[x[b,s],e]*Wih[n,e] + sum_t key[b,s,t]*Wkh[n,t] + bg[n]
// GEMM: M = B*CH (rows m = b*CH + sl), N = 1024, K = 512 (300 emb + 200 key + 12 pad)
// tile 128x128, 256 threads, 8x8 micro (split row/col halves for bank spread)
// LDS layout transposed: As[k][slot'] with slot' = ((row>>2)+k)&31, 4 floats/slot
// ---------------------------------------------------------------------------
__global__ __launch_bounds__(256) void gemm_g(
    const int* __restrict__ x1, const int* __restrict__ x2,
    const float* __restrict__ key_c, const float* __restrict__ key_r,
    const float* __restrict__ emb, const float* __restrict__ Wih,
    const float* __restrict__ Wkh, const float* __restrict__ bg,
    float* __restrict__ G, int s0)
{
    __shared__ __align__(16) float As[16 * 128];
    __shared__ __align__(16) float Bs[16 * 128];
    __shared__ int ridx[128];
    __shared__ int kbas[128];

    const int t   = threadIdx.x;
    const int rnn = blockIdx.z;
    const int m0  = blockIdx.x * 128;
    const int n0  = blockIdx.y * 128;
    const int* xx = rnn ? x2 : x1;
    const float* key = rnn ? key_r : key_c;

    if (t < 128) {
        int m = m0 + t;
        int b = m >> 4;
        int s = s0 + (m & 15);
        int bs = b * S_ + s;
        ridx[t] = xx[bs] * E_;
        kbas[t] = bs * T_;
    }

    float acc[8][8];
    #pragma unroll
    for (int i = 0; i < 8; ++i)
        #pragma unroll
        for (int j = 0; j < 8; ++j) acc[i][j] = 0.0f;

    const int ty = t >> 4;      // 0..15
    const int tx = t & 15;      // 0..15
    const int lrow = t >> 1;    // 0..127
    const int kh = (t & 1) * 8; // 0 or 8

    for (int kt = 0; kt < 32; ++kt) {
        const int k0 = kt * 16;
        __syncthreads();
        {
            const int eb = ridx[lrow];
            const int kb = kbas[lrow];
            const int slot = lrow >> 2;
            const int rlo  = lrow & 3;
            #pragma unroll
            for (int ii = 0; ii < 8; ++ii) {
                int k  = kh + ii;
                int kg = k0 + k;
                float v = 0.0f;
                if (kg < E_)            v = emb[eb + kg];
                else if (kg < E_ + T_)  v = key[kb + kg - E_];
                As[k * 128 + ((slot + k) & 31) * 4 + rlo] = v;
            }
            const int n = n0 + lrow;
            const float* wih = Wih + n * E_;
            const float* wkh = Wkh + n * T_;
            #pragma unroll
            for (int ii = 0; ii < 8; ++ii) {
                int k  = kh + ii;
                int kg = k0 + k;
                float v = 0.0f;
                if (kg < E_)            v = wih[kg];
                else if (kg < E_ + T_)  v = wkh[kg - E_];
                Bs[k * 128 + ((slot + k) & 31) * 4 + rlo] = v;
            }
        }
        __syncthreads();
        #pragma unroll
        for (int kk = 0; kk < 16; ++kk) {
            const float4 a0 = *(const float4*)&As[kk * 128 + ((ty + kk) & 31) * 4];
            const float4 a1 = *(const float4*)&As[kk * 128 + ((16 + ty + kk) & 31) * 4];
            const float4 b0 = *(const float4*)&Bs[kk * 128 + ((tx + kk) & 31) * 4];
            const float4 b1 = *(const float4*)&Bs[kk * 128 + ((16 + tx + kk) & 31) * 4];
            const float av[8] = {a0.x, a0.y, a0.z, a0.w, a1.x, a1.y, a1.z, a1.w};
            const float bv[8] = {b0.x, b0.y, b0.z, b0.w, b1.x, b1.y, b1.z, b1.w};
            #pragma unroll
            for (int i = 0; i < 8; ++i)
                #pragma unroll
                for (int j = 0; j < 8; ++j)
                    acc[i][j] = fmaf(av[i], bv[j], acc[i][j]);
        }
    }

    float bgl[8];
    #pragma unroll
    for (int j = 0; j < 4; ++j) {
        bgl[j]     = bg[n0 + tx * 4 + j];
        bgl[4 + j] = bg[n0 + 64 + tx * 4 + j];
    }
    #pragma unroll
    for (int i = 0; i < 8; ++i) {
        int row = (i < 4) ? (ty * 4 + i) : (64 + ty * 4 + (i - 4));
        int m  = m0 + row;
        int b  = m >> 4;
        int sl = m & 15;
        float* dst = G + (((size_t)(rnn * CH + sl) * B_ + b) * G4H) + n0;
        float4 v0 = make_float4(acc[i][0] + bgl[0], acc[i][1] + bgl[1],
                                acc[i][2] + bgl[2], acc[i][3] + bgl[3]);
        float4 v1 = make_float4(acc[i][4] + bgl[4], acc[i][5] + bgl[5],
                                acc[i][6] + bgl[6], acc[i][7] + bgl[7]);
        *(float4*)&dst[tx * 4]      = v0;
        *(float4*)&dst[64 + tx * 4] = v1;
    }
}

// ---------------------------------------------------------------------------
// One LSTM step for both RNNs. Tile: 32 batch rows x 32 gate-cols
// (8 j-cols x 4 gates), 64 threads (1 wave), 4x4 micro-tile.
// Phase 1: g_hh tile = h_prev @ Whh.T   (K=256 in 4 chunks of 64)
// Phase 2: gates += G, nonlinearity, update c (in-place), h (double-buffered)
// ---------------------------------------------------------------------------
__global__ __launch_bounds__(64) void lstm_step(
    const float* __restrict__ G, const float* __restrict__ Whh,
    float* __restrict__ hbuf, float* __restrict__ cbuf,
    float* __restrict__ sc,
    int sl, int s_glob, int p_in)
{
    __shared__ __align__(16) float HsT[64 * 32];
    __shared__ __align__(16) float WsT[64 * 32];
    __shared__ float gs[32][33];

    const int t   = threadIdx.x;
    const int rnn = blockIdx.z;
    const int b0  = blockIdx.x * 32;
    const int J0  = blockIdx.y * 8;

    const float* hprev = hbuf + (size_t)(rnn * 2 + p_in) * (B_ * H_);

    float acc[4][4];
    #pragma unroll
    for (int i = 0; i < 4; ++i)
        #pragma unroll
        for (int j = 0; j < 4; ++j) acc[i][j] = 0.0f;

    const int ty = t >> 3;   // 0..7
    const int tx = t & 7;    // 0..7
    const int lrow = t >> 1; // 0..31
    const int kh4  = (t & 1) * 8;
    // W staging: tile row nn = lrow: gate = nn>>3, jj = nn&7
    const int ngl = ((lrow >> 3) * H_) + J0 + (lrow & 7);

    for (int kc = 0; kc < 4; ++kc) {
        const int k0 = kc * 64;
        __syncthreads();
        {
            const float* hsrc = hprev + (size_t)(b0 + lrow) * H_ + k0;
            const float* wsrc = Whh + (size_t)ngl * H_ + k0;
            const int slot = lrow >> 2;
            const int rlo  = lrow & 3;
            #pragma unroll
            for (int i4 = 0; i4 < 8; ++i4) {
                int k4 = kh4 + i4;  // 0..15
                float4 hv = *(const float4*)&hsrc[k4 * 4];
                float4 wv = *(const float4*)&wsrc[k4 * 4];
                const float hvv[4] = {hv.x, hv.y, hv.z, hv.w};
                const float wvv[4] = {wv.x, wv.y, wv.z, wv.w};
                #pragma unroll
                for (int j = 0; j < 4; ++j) {
                    int k   = k4 * 4 + j;
                    int dst = k * 32 + ((slot + k) & 7) * 4 + rlo;
                    HsT[dst] = hvv[j];
                    WsT[dst] = wvv[j];
                }
            }
        }
        __syncthreads();
        #pragma unroll 16
        for (int kk = 0; kk < 64; ++kk) {
            const float4 a = *(const float4*)&HsT[kk * 32 + ((ty + kk) & 7) * 4];
            const float4 w = *(const float4*)&WsT[kk * 32 + ((tx + kk) & 7) * 4];
            const float av[4] = {a.x, a.y, a.z, a.w};
            const float wv[4] = {w.x, w.y, w.z, w.w};
            #pragma unroll
            for (int i = 0; i < 4; ++i)
                #pragma unroll
                for (int j = 0; j < 4; ++j)
                    acc[i][j] = fmaf(av[i], wv[j], acc[i][j]);
        }
    }

    #pragma unroll
    for (int i = 0; i < 4; ++i)
        #pragma unroll
        for (int j = 0; j < 4; ++j)
            gs[ty * 4 + i][tx * 4 + j] = acc[i][j];
    __syncthreads();

    const float* Gpl = G + (size_t)(rnn * CH + sl) * B_ * G4H;
    float* hout = hbuf + (size_t)(rnn * 2 + (1 - p_in)) * (B_ * H_);

    #pragma unroll
    for (int it = 0; it < 4; ++it) {
        int pair = it * 64 + t;
        int bl = pair >> 3;
        int jj = pair & 7;
        int b  = b0 + bl;
        int j  = J0 + jj;
        const float* gr = Gpl + (size_t)b * G4H + j;
        float gi = gs[bl][jj]      + gr[0];
        float gf = gs[bl][8 + jj]  + gr[H_];
        float gg = gs[bl][16 + jj] + gr[2 * H_];
        float go = gs[bl][24 + jj] + gr[3 * H_];
        int ci = rnn * (B_ * H_) + b * H_ + j;
        float c = sigf(gf) * cbuf[ci] + sigf(gi) * tanhf(gg);
        float h = sigf(go) * tanhf(c);
        cbuf[ci] = c;
        hout[b * H_ + j] = h;
        if (rnn == 0) sc[((size_t)b * S_ + s_glob) * H_ + j] = h;
    }
}

// ---------------------------------------------------------------------------
// Fused attention epilogue, one block per batch row b:
// u[k] = sum_h r[h]*Wattn[h,k]; beta = sum_h battn[h]*r[h]; v[h] = sum_k M[h,k]*r[k]
// e[s] = (sc[b,s,:].u + beta)*mask; softmax; c_attn = sum_s alpha*sc; o = c_attn.v + b0
// ---------------------------------------------------------------------------
__global__ __launch_bounds__(256) void final_kernel(
    const float* __restrict__ sc, const float* __restrict__ r,
    const float* __restrict__ Wattn, const float* __restrict__ battn,
    const float* __restrict__ M, const float* __restrict__ bscal,
    const float* __restrict__ mask, float* __restrict__ out)
{
    __shared__ float rs[256], us[256], red[256], as_[256];
    const int b = blockIdx.x;
    const int t = threadIdx.x;

    rs[t] = r[b * 256 + t];
    __syncthreads();

    float acc = 0.0f;
    for (int h = 0; h < 256; ++h) acc += rs[h] * Wattn[h * 256 + t];
    us[t] = acc;

    red[t] = battn[t] * rs[t];
    __syncthreads();
    for (int off = 128; off; off >>= 1) {
        if (t < off) red[t] += red[t + off];
        __syncthreads();
    }
    float beta = red[0];
    __syncthreads();

    float vh = 0.0f;
    {
        const float* Mrow = M + t * 256;
        for (int k = 0; k < 256; ++k) vh += Mrow[k] * rs[k];
    }

    float e = -INFINITY;
    if (t < S_) {
        float d = 0.0f;
        const float* scrow = sc + ((size_t)b * S_ + t) * H_;
        for (int h = 0; h < 256; ++h) d += scrow[h] * us[h];
        e = (d + beta) * mask[b * S_ + t];
    }
    red[t] = e;
    __syncthreads();
    for (int off = 128; off; off >>= 1) {
        if (t < off) red[t] = fmaxf(red[t], red[t + off]);
        __syncthreads();
    }
    float mx = red[0];
    __syncthreads();

    float p = (t < S_) ? expf(e - mx) : 0.0f;
    as_[t] = p;
    red[t] = p;
    __syncthreads();
    for (int off = 128; off; off >>= 1) {
        if (t < off) red[t] += red[t + off];
        __syncthreads();
    }
    float inv = 1.0f / red[0];
    __syncthreads();

    float ca = 0.0f;
    for (int s = 0; s < S_; ++s) ca += as_[s] * sc[((size_t)b * S_ + s) * H_ + t];
    ca *= inv;

    red[t] = ca * vh;
    __syncthreads();
    for (int off = 128; off; off >>= 1) {
        if (t < off) red[t] += red[t + off];
        __syncthreads();
    }
    if (t == 0) out[b] = red[0] + bscal[0];
}

// ---------------------------------------------------------------------------
extern "C" void kernel_launch(void* const* d_in, const int* in_sizes, int n_in,
                              void* d_out, int out_size, void* d_ws, size_t ws_size,
                              hipStream_t stream)
{
    const int*   x1    = (const int*)d_in[0];
    const int*   x2    = (const int*)d_in[1];
    const float* mask  = (const float*)d_in[2];
    const float* key_c = (const float*)d_in[3];
    const float* key_r = (const float*)d_in[4];
    const float* emb   = (const float*)d_in[5];
    const float* Wih   = (const float*)d_in[6];
    const float* Whh   = (const float*)d_in[7];
    const float* Wkh   = (const float*)d_in[8];
    const float* bg    = (const float*)d_in[9];
    const float* Wattn = (const float*)d_in[10];
    const float* battn = (const float*)d_in[11];
    const float* M     = (const float*)d_in[12];
    const float* bb    = (const float*)d_in[13];
    float* out = (float*)d_out;
    float* ws  = (float*)d_ws;

    const size_t off_sc = 0;
    const size_t off_G  = off_sc + (size_t)B_ * S_ * H_;        // 10,485,760
    const size_t off_h  = off_G + (size_t)2 * CH * B_ * G4H;    // +8,388,608
    const size_t off_c  = off_h + (size_t)4 * B_ * H_;
    const size_t total  = off_c + (size_t)2 * B_ * H_;
    if (ws_size < total * sizeof(float)) return;  // workspace too small: fail visibly

    float* sc   = ws + off_sc;
    float* G    = ws + off_G;
    float* hbuf = ws + off_h;
    float* cbuf = ws + off_c;

    // zero h (both parities, both RNNs) and c
    hipMemsetAsync(hbuf, 0, (size_t)(6 * B_ * H_) * sizeof(float), stream);

    for (int ci = 0; ci < NCH; ++ci) {
        gemm_g<<<dim3(32, 8, 2), 256, 0, stream>>>(x1, x2, key_c, key_r, emb,
                                                   Wih, Wkh, bg, G, ci * CH);
        for (int slq = 0; slq < CH; ++slq) {
            int tstep = ci * CH + slq;
            lstm_step<<<dim3(8, 32, 2), 64, 0, stream>>>(G, Whh, hbuf, cbuf, sc,
                                                         slq, tstep, tstep & 1);
        }
    }

    const float* rfin = hbuf + (size_t)(1 * 2 + 0) * (B_ * H_);
    final_kernel<<<dim3(256), 256, 0, stream>>>(sc, rfin, Wattn, battn, M, bb, mask, out);
}

// Round 2
// 2617.198 us; speedup vs baseline: 1.8825x; 1.8825x over previous
//
#include <hip/hip_runtime.h>
#include <math.h>

#define B_   256
#define S_   160
#define E_   300
#define H_   256
#define T_   200
#define G4H  1024
#define CH   16
#define NCH  10

__device__ __forceinline__ float sigf(float x) {
    float e = expf(-fabsf(x));
    float p = 1.0f / (1.0f + e);
    return x >= 0.0f ? p : e * p;
}

// load 4 consecutive K-values from the concatenated [emb(300) | key(200) | pad] row
__device__ __forceinline__ float4 load_ek(const float* __restrict__ eb,
                                          const float* __restrict__ kb, int kg) {
    if (kg < E_)      return *(const float4*)(eb + kg);
    if (kg < E_ + T_) return *(const float4*)(kb + (kg - E_));
    return make_float4(0.f, 0.f, 0.f, 0.f);
}

// ---------------------------------------------------------------------------
// G[rnn, sl, b, n] = emb[x[b,s],:]@Wih[n,:] + key[b,s,:]@Wkh[n,:] + bg[n]
// M = B*CH rows (m = b*CH+sl), N = 1024, K = 512 (300+200+12 pad)
// Tile 128x64, BK=16, 256 threads, micro 8x4.
// LDS layout [k][row]: A-frag = 8 contiguous rows (2xb128, broadcast across 16
// lanes -> conflict-free), B-frag = 4 contiguous cols (2-way = free).
// ---------------------------------------------------------------------------
__global__ __launch_bounds__(256, 4) void gemm_g(
    const int* __restrict__ x1, const int* __restrict__ x2,
    const float* __restrict__ key_c, const float* __restrict__ key_r,
    const float* __restrict__ emb, const float* __restrict__ Wih,
    const float* __restrict__ Wkh, const float* __restrict__ bg,
    float* __restrict__ G, int s0)
{
    __shared__ __align__(16) float As[16 * 128];
    __shared__ __align__(16) float Bs[16 * 64];

    const int t   = threadIdx.x;
    const int rnn = blockIdx.z;
    const int m0  = blockIdx.x * 128;
    const int n0  = blockIdx.y * 64;
    const int* xx = rnn ? x2 : x1;
    const float* key = rnn ? key_r : key_c;

    // A staging: thread owns row arow, k-halves akh..akh+7 of each 16-k tile
    const int arow = t >> 1;          // 0..127
    const int akh  = (t & 1) * 8;     // 0 or 8
    const int am   = m0 + arow;
    const int ab   = am >> 4;
    const int as   = s0 + (am & 15);
    const int absi = ab * S_ + as;
    const float* aeb = emb + (size_t)xx[absi] * E_;
    const float* akb = key + (size_t)absi * T_;

    // B staging: thread owns weight-row brow, 4 k's
    const int brow = t >> 2;          // 0..63
    const int bkh  = (t & 3) * 4;     // 0,4,8,12
    const int bn   = n0 + brow;
    const float* weh = Wih + (size_t)bn * E_;
    const float* wkb = Wkh + (size_t)bn * T_;

    const int ty = t >> 4;            // 0..15 -> rows 8*ty..8*ty+7
    const int tx = t & 15;            // 0..15 -> cols 4*tx..4*tx+3

    float acc[8][4];
    #pragma unroll
    for (int i = 0; i < 8; ++i)
        #pragma unroll
        for (int j = 0; j < 4; ++j) acc[i][j] = 0.0f;

    for (int kt = 0; kt < 32; ++kt) {
        const int k0 = kt * 16;
        __syncthreads();
        {
            const float4 v0 = load_ek(aeb, akb, k0 + akh);
            const float4 v1 = load_ek(aeb, akb, k0 + akh + 4);
            As[(akh + 0) * 128 + arow] = v0.x;
            As[(akh + 1) * 128 + arow] = v0.y;
            As[(akh + 2) * 128 + arow] = v0.z;
            As[(akh + 3) * 128 + arow] = v0.w;
            As[(akh + 4) * 128 + arow] = v1.x;
            As[(akh + 5) * 128 + arow] = v1.y;
            As[(akh + 6) * 128 + arow] = v1.z;
            As[(akh + 7) * 128 + arow] = v1.w;
            const float4 w0 = load_ek(weh, wkb, k0 + bkh);
            Bs[(bkh + 0) * 64 + brow] = w0.x;
            Bs[(bkh + 1) * 64 + brow] = w0.y;
            Bs[(bkh + 2) * 64 + brow] = w0.z;
            Bs[(bkh + 3) * 64 + brow] = w0.w;
        }
        __syncthreads();
        #pragma unroll
        for (int kk = 0; kk < 16; ++kk) {
            const float4 a0 = *(const float4*)&As[kk * 128 + 8 * ty];
            const float4 a1 = *(const float4*)&As[kk * 128 + 8 * ty + 4];
            const float4 b0 = *(const float4*)&Bs[kk * 64 + 4 * tx];
            const float av[8] = {a0.x, a0.y, a0.z, a0.w, a1.x, a1.y, a1.z, a1.w};
            const float bv[4] = {b0.x, b0.y, b0.z, b0.w};
            #pragma unroll
            for (int i = 0; i < 8; ++i)
                #pragma unroll
                for (int j = 0; j < 4; ++j)
                    acc[i][j] = fmaf(av[i], bv[j], acc[i][j]);
        }
    }

    const float4 bgv = *(const float4*)&bg[n0 + 4 * tx];
    #pragma unroll
    for (int i = 0; i < 8; ++i) {
        const int m  = m0 + 8 * ty + i;
        const int b  = m >> 4;
        const int sl = m & 15;
        float* dst = G + (((size_t)(rnn * CH + sl) * B_ + b) * G4H) + n0 + 4 * tx;
        float4 o;
        o.x = acc[i][0] + bgv.x;
        o.y = acc[i][1] + bgv.y;
        o.z = acc[i][2] + bgv.z;
        o.w = acc[i][3] + bgv.w;
        *(float4*)dst = o;
    }
}

// ---------------------------------------------------------------------------
// One LSTM step, both RNNs (row r = rnn*256 + b).
// Block: 256 threads = 4 waves; output tile 32 b-rows x (4 gates x 8 j).
// Waves K-split K=256 into 4 chunks of 64; LDS [w][k][row] staging (conflict-
// free broadcast reads); partial sums reduced via LDS (aliased over Hs);
// fused gate math + c/h update + sc write.
// ---------------------------------------------------------------------------
__global__ __launch_bounds__(256) void lstm_step(
    const float* __restrict__ G, const float* __restrict__ Whh,
    float* __restrict__ hbuf, float* __restrict__ cbuf,
    float* __restrict__ sc, int sl, int s_glob, int p_in)
{
    __shared__ __align__(16) float Hs[4 * 64 * 32];   // 32 KB, also psum alias
    __shared__ __align__(16) float Ws[4 * 64 * 32];   // 32 KB

    const int t    = threadIdx.x;
    const int w    = t >> 6;          // K-chunk / wave id
    const int lane = t & 63;
    const int rnn  = blockIdx.x >> 3;
    const int b0   = (blockIdx.x * 32) & 255;
    const int J0   = blockIdx.y * 8;

    const float* hprev = hbuf + (size_t)(rnn * 2 + p_in) * (B_ * H_);

    // stage this wave's K-chunk: h rows b0..b0+31 and W rows (gate,j) slots 0..31
    {
        const int row = lane >> 1;              // 0..31 (slot index)
        const int kin = (lane & 1) * 32;        // k offset within chunk
        const int kh  = w * 64 + kin;
        const float* hsrc = hprev + (size_t)(b0 + row) * H_ + kh;
        const int wrow = (row >> 3) * H_ + J0 + (row & 7);   // gate*256 + J0 + jj
        const float* wsrc = Whh + (size_t)wrow * H_ + kh;
        float* hd = &Hs[w * (64 * 32)];
        float* wd = &Ws[w * (64 * 32)];
        #pragma unroll
        for (int i = 0; i < 8; ++i) {
            const float4 hv = *(const float4*)(hsrc + 4 * i);
            const float4 wv = *(const float4*)(wsrc + 4 * i);
            const int kb = kin + 4 * i;
            hd[(kb + 0) * 32 + row] = hv.x;
            hd[(kb + 1) * 32 + row] = hv.y;
            hd[(kb + 2) * 32 + row] = hv.z;
            hd[(kb + 3) * 32 + row] = hv.w;
            wd[(kb + 0) * 32 + row] = wv.x;
            wd[(kb + 1) * 32 + row] = wv.y;
            wd[(kb + 2) * 32 + row] = wv.z;
            wd[(kb + 3) * 32 + row] = wv.w;
        }
    }
    __syncthreads();

    const int ty = lane >> 3;   // rows 4*ty..4*ty+3
    const int tx = lane & 7;    // slot cols 4*tx..4*tx+3
    float acc[4][4];
    #pragma unroll
    for (int i = 0; i < 4; ++i)
        #pragma unroll
        for (int j = 0; j < 4; ++j) acc[i][j] = 0.0f;

    const float* hS = &Hs[w * (64 * 32)];
    const float* wS = &Ws[w * (64 * 32)];
    #pragma unroll 8
    for (int kk = 0; kk < 64; ++kk) {
        const float4 a = *(const float4*)&hS[kk * 32 + 4 * ty];
        const float4 v = *(const float4*)&wS[kk * 32 + 4 * tx];
        const float av[4] = {a.x, a.y, a.z, a.w};
        const float vv[4] = {v.x, v.y, v.z, v.w};
        #pragma unroll
        for (int i = 0; i < 4; ++i)
            #pragma unroll
            for (int j = 0; j < 4; ++j)
                acc[i][j] = fmaf(av[i], vv[j], acc[i][j]);
    }
    __syncthreads();

    // write partials into psum alias [4][32][33] over Hs
    float* ps = Hs;
    #pragma unroll
    for (int i = 0; i < 4; ++i)
        #pragma unroll
        for (int j = 0; j < 4; ++j)
            ps[w * (32 * 33) + (4 * ty + i) * 33 + (4 * tx + j)] = acc[i][j];
    __syncthreads();

    // epilogue: thread -> (batch row bl, j col jj); reduce 4 waves, gate math
    const int bl = t >> 3;      // 0..31
    const int jj = t & 7;       // 0..7
    const int b  = b0 + bl;
    const int j  = J0 + jj;
    float g4[4];
    #pragma unroll
    for (int gt = 0; gt < 4; ++gt) {
        const int c0 = bl * 33 + gt * 8 + jj;
        g4[gt] = ps[c0] + ps[1056 + c0] + ps[2112 + c0] + ps[3168 + c0];
    }
    const float* Gr = G + ((size_t)(rnn * CH + sl) * B_ + b) * G4H + j;
    const float gi = g4[0] + Gr[0];
    const float gf = g4[1] + Gr[H_];
    const float gg = g4[2] + Gr[2 * H_];
    const float go = g4[3] + Gr[3 * H_];
    const int ci = rnn * (B_ * H_) + b * H_ + j;
    const float c = sigf(gf) * cbuf[ci] + sigf(gi) * tanhf(gg);
    const float h = sigf(go) * tanhf(c);
    cbuf[ci] = c;
    hbuf[(size_t)(rnn * 2 + (1 - p_in)) * (B_ * H_) + b * H_ + j] = h;
    if (rnn == 0) sc[((size_t)b * S_ + s_glob) * H_ + j] = h;
}

// ---------------------------------------------------------------------------
// Fused attention epilogue, one block per batch row b.
// ---------------------------------------------------------------------------
__global__ __launch_bounds__(256) void final_kernel(
    const float* __restrict__ sc, const float* __restrict__ r,
    const float* __restrict__ Wattn, const float* __restrict__ battn,
    const float* __restrict__ M, const float* __restrict__ bscal,
    const float* __restrict__ mask, float* __restrict__ out)
{
    __shared__ float rs[256], us[256], red[256], as_[256];
    const int b = blockIdx.x;
    const int t = threadIdx.x;

    rs[t] = r[b * 256 + t];
    __syncthreads();

    float acc = 0.0f;
    for (int h = 0; h < 256; ++h) acc += rs[h] * Wattn[h * 256 + t];
    us[t] = acc;

    red[t] = battn[t] * rs[t];
    __syncthreads();
    for (int off = 128; off; off >>= 1) {
        if (t < off) red[t] += red[t + off];
        __syncthreads();
    }
    float beta = red[0];
    __syncthreads();

    float vh = 0.0f;
    {
        const float* Mrow = M + t * 256;
        for (int k = 0; k < 256; ++k) vh += Mrow[k] * rs[k];
    }

    float e = -INFINITY;
    if (t < S_) {
        float d = 0.0f;
        const float* scrow = sc + ((size_t)b * S_ + t) * H_;
        for (int h = 0; h < 256; ++h) d += scrow[h] * us[h];
        e = (d + beta) * mask[b * S_ + t];
    }
    red[t] = e;
    __syncthreads();
    for (int off = 128; off; off >>= 1) {
        if (t < off) red[t] = fmaxf(red[t], red[t + off]);
        __syncthreads();
    }
    float mx = red[0];
    __syncthreads();

    float p = (t < S_) ? expf(e - mx) : 0.0f;
    as_[t] = p;
    red[t] = p;
    __syncthreads();
    for (int off = 128; off; off >>= 1) {
        if (t < off) red[t] += red[t + off];
        __syncthreads();
    }
    float inv = 1.0f / red[0];
    __syncthreads();

    float ca = 0.0f;
    for (int s = 0; s < S_; ++s) ca += as_[s] * sc[((size_t)b * S_ + s) * H_ + t];
    ca *= inv;

    red[t] = ca * vh;
    __syncthreads();
    for (int off = 128; off; off >>= 1) {
        if (t < off) red[t] += red[t + off];
        __syncthreads();
    }
    if (t == 0) out[b] = red[0] + bscal[0];
}

// ---------------------------------------------------------------------------
extern "C" void kernel_launch(void* const* d_in, const int* in_sizes, int n_in,
                              void* d_out, int out_size, void* d_ws, size_t ws_size,
                              hipStream_t stream)
{
    const int*   x1    = (const int*)d_in[0];
    const int*   x2    = (const int*)d_in[1];
    const float* mask  = (const float*)d_in[2];
    const float* key_c = (const float*)d_in[3];
    const float* key_r = (const float*)d_in[4];
    const float* emb   = (const float*)d_in[5];
    const float* Wih   = (const float*)d_in[6];
    const float* Whh   = (const float*)d_in[7];
    const float* Wkh   = (const float*)d_in[8];
    const float* bg    = (const float*)d_in[9];
    const float* Wattn = (const float*)d_in[10];
    const float* battn = (const float*)d_in[11];
    const float* M     = (const float*)d_in[12];
    const float* bb    = (const float*)d_in[13];
    float* out = (float*)d_out;
    float* ws  = (float*)d_ws;

    const size_t off_sc = 0;
    const size_t off_G  = off_sc + (size_t)B_ * S_ * H_;        // 10,485,760
    const size_t off_h  = off_G + (size_t)2 * CH * B_ * G4H;    // +8,388,608
    const size_t off_c  = off_h + (size_t)4 * B_ * H_;
    const size_t total  = off_c + (size_t)2 * B_ * H_;
    if (ws_size < total * sizeof(float)) return;  // workspace too small: fail visibly

    float* sc   = ws + off_sc;
    float* G    = ws + off_G;
    float* hbuf = ws + off_h;
    float* cbuf = ws + off_c;

    // zero h (both parities, both RNNs) and c
    hipMemsetAsync(hbuf, 0, (size_t)(6 * B_ * H_) * sizeof(float), stream);

    for (int ci = 0; ci < NCH; ++ci) {
        gemm_g<<<dim3(32, 16, 2), 256, 0, stream>>>(x1, x2, key_c, key_r, emb,
                                                    Wih, Wkh, bg, G, ci * CH);
        for (int slq = 0; slq < CH; ++slq) {
            int tstep = ci * CH + slq;
            lstm_step<<<dim3(16, 32), 256, 0, stream>>>(G, Whh, hbuf, cbuf, sc,
                                                        slq, tstep, tstep & 1);
        }
    }

    const float* rfin = hbuf + (size_t)(1 * 2 + 0) * (B_ * H_);
    final_kernel<<<dim3(256), 256, 0, stream>>>(sc, rfin, Wattn, battn, M, bb, mask, out);
}

// Round 3
// 2022.761 us; speedup vs baseline: 2.4357x; 1.2939x over previous
//
#include <hip/hip_runtime.h>
#include <math.h>

#define B_   256
#define S_   160
#define E_   300
#define H_   256
#define T_   200
#define G4H  1024
#define CH   16
#define NCH  10

typedef float  f32x4  __attribute__((ext_vector_type(4)));
typedef __bf16 bf16x4 __attribute__((ext_vector_type(4)));
typedef __bf16 bf16x8 __attribute__((ext_vector_type(8)));

__device__ __forceinline__ float sigf(float x) {
    float e = expf(-fabsf(x));
    float p = 1.0f / (1.0f + e);
    return x >= 0.0f ? p : e * p;
}

// 4 consecutive K-values from concatenated [first(300) | second(200) | pad] row
__device__ __forceinline__ float4 pick4(const float* __restrict__ e,
                                        const float* __restrict__ k, int kg) {
    if (kg < E_)      return *(const float4*)(e + kg);
    if (kg < E_ + T_) return *(const float4*)(k + (kg - E_));
    return make_float4(0.f, 0.f, 0.f, 0.f);
}

__device__ __forceinline__ void split4(float4 v, bf16x4& h, bf16x4& l) {
    h[0] = (__bf16)v.x; l[0] = (__bf16)(v.x - (float)h[0]);
    h[1] = (__bf16)v.y; l[1] = (__bf16)(v.y - (float)h[1]);
    h[2] = (__bf16)v.z; l[2] = (__bf16)(v.z - (float)h[2]);
    h[3] = (__bf16)v.w; l[3] = (__bf16)(v.w - (float)h[3]);
}

// ---------------------------------------------------------------------------
// G[rnn, sl, b, n] = emb[x[b,s],:]@Wih[n,:] + key[b,s,:]@Wkh[n,:] + bg[n]
// Split-bf16 MFMA GEMM: G = Ah·Bh + Ah·Bl + Al·Bh (fp32-class accuracy).
// M = 4096 (m = b*16+sl), N = 1024, K = 512 (300+200+12 pad), tile 128x128,
// BK = 32, 256 threads = 4 waves (2x2 of 64x64), mfma_f32_16x16x32_bf16.
// LDS [row][32k] bf16 with 16B-chunk XOR swizzle: chunk' = chunk ^ ((row>>1)&3)
// -> ds_write_b64 staging conflict-free, ds_read_b128 frags 2-way (free).
// ---------------------------------------------------------------------------
__global__ __launch_bounds__(256, 2) void gemm_g2(
    const int* __restrict__ x1, const int* __restrict__ x2,
    const float* __restrict__ key_c, const float* __restrict__ key_r,
    const float* __restrict__ emb, const float* __restrict__ Wih,
    const float* __restrict__ Wkh, const float* __restrict__ bg,
    float* __restrict__ G, int s0)
{
    __shared__ __align__(16) __bf16 Ah[128 * 32];
    __shared__ __align__(16) __bf16 Al[128 * 32];
    __shared__ __align__(16) __bf16 Bh[128 * 32];
    __shared__ __align__(16) __bf16 Bl[128 * 32];

    const int t   = threadIdx.x;
    const int rnn = blockIdx.z;
    const int m0  = blockIdx.x * 128;
    const int n0  = blockIdx.y * 128;
    const int* xx = rnn ? x2 : x1;
    const float* key = rnn ? key_r : key_c;

    // ---- staging thread mapping: 4 rows (r0+32i) x 4 k's (kq*4) ----
    const int r0  = t >> 3;                 // 0..31
    const int kq  = t & 7;                  // k-quad within BK=32
    const int csw = (((kq >> 1) ^ ((r0 >> 1) & 3)) * 16) + (kq & 1) * 8;

    const float* aeb[4]; const float* akb[4];
    const float* wv1[4]; const float* wv2[4];
    #pragma unroll
    for (int i = 0; i < 4; ++i) {
        const int row = r0 + 32 * i;
        const int am  = m0 + row;
        const int bs  = (am >> 4) * S_ + s0 + (am & 15);
        aeb[i] = emb + (size_t)xx[bs] * E_;
        akb[i] = key + (size_t)bs * T_;
        const int n = n0 + row;
        wv1[i] = Wih + (size_t)n * E_;
        wv2[i] = Wkh + (size_t)n * T_;
    }

    // ---- compute thread mapping ----
    const int w  = t >> 6;      // wave id
    const int wm = w >> 1;      // 0..1 (m half)
    const int wn = w & 1;       // 0..1 (n half)
    const int l  = t & 63;
    const int cl = l & 15;      // row-within-16 for A/B frags; col for C
    const int ch = l >> 4;      // k-chunk for frags; row-group for C
    const int chs = ((ch ^ ((cl >> 1) & 3)) * 16);

    f32x4 acc[4][4];
    #pragma unroll
    for (int fm = 0; fm < 4; ++fm)
        #pragma unroll
        for (int fn = 0; fn < 4; ++fn) acc[fm][fn] = (f32x4){0.f, 0.f, 0.f, 0.f};

    for (int kt = 0; kt < 16; ++kt) {
        const int kg = kt * 32 + kq * 4;
        bf16x4 sAh[4], sAl[4], sBh[4], sBl[4];
        #pragma unroll
        for (int i = 0; i < 4; ++i) {
            const float4 va = pick4(aeb[i], akb[i], kg);
            const float4 vb = pick4(wv1[i], wv2[i], kg);
            split4(va, sAh[i], sAl[i]);
            split4(vb, sBh[i], sBl[i]);
        }
        __syncthreads();
        #pragma unroll
        for (int i = 0; i < 4; ++i) {
            const int off = (r0 + 32 * i) * 64 + csw;
            *(bf16x4*)((char*)Ah + off) = sAh[i];
            *(bf16x4*)((char*)Al + off) = sAl[i];
            *(bf16x4*)((char*)Bh + off) = sBh[i];
            *(bf16x4*)((char*)Bl + off) = sBl[i];
        }
        __syncthreads();

        bf16x8 fBh[4], fBl[4];
        #pragma unroll
        for (int fn = 0; fn < 4; ++fn) {
            const int off = (wn * 64 + fn * 16 + cl) * 64 + chs;
            fBh[fn] = *(const bf16x8*)((const char*)Bh + off);
            fBl[fn] = *(const bf16x8*)((const char*)Bl + off);
        }
        #pragma unroll
        for (int fm = 0; fm < 4; ++fm) {
            const int off = (wm * 64 + fm * 16 + cl) * 64 + chs;
            const bf16x8 fAh = *(const bf16x8*)((const char*)Ah + off);
            const bf16x8 fAl = *(const bf16x8*)((const char*)Al + off);
            #pragma unroll
            for (int fn = 0; fn < 4; ++fn) {
                acc[fm][fn] = __builtin_amdgcn_mfma_f32_16x16x32_bf16(fAh, fBh[fn], acc[fm][fn], 0, 0, 0);
                acc[fm][fn] = __builtin_amdgcn_mfma_f32_16x16x32_bf16(fAh, fBl[fn], acc[fm][fn], 0, 0, 0);
                acc[fm][fn] = __builtin_amdgcn_mfma_f32_16x16x32_bf16(fAl, fBh[fn], acc[fm][fn], 0, 0, 0);
            }
        }
    }

    // ---- epilogue: C layout col = lane&15, row = (lane>>4)*4 + reg ----
    float bgl[4];
    #pragma unroll
    for (int fn = 0; fn < 4; ++fn) bgl[fn] = bg[n0 + wn * 64 + fn * 16 + cl];

    #pragma unroll
    for (int fm = 0; fm < 4; ++fm) {
        #pragma unroll
        for (int r = 0; r < 4; ++r) {
            const int m  = m0 + wm * 64 + fm * 16 + ch * 4 + r;
            const int b  = m >> 4;
            const int sl = m & 15;
            float* rowp = G + ((size_t)(rnn * CH + sl) * B_ + b) * G4H;
            #pragma unroll
            for (int fn = 0; fn < 4; ++fn)
                rowp[n0 + wn * 64 + fn * 16 + cl] = acc[fm][fn][r] + bgl[fn];
        }
    }
}

// ---------------------------------------------------------------------------
// One LSTM step, both RNNs. 256 threads = 4 waves; tile 32 b-rows x 32 gates;
// waves K-split K=256; LDS [w][k][row] staging; psum reduce via LDS alias.
// ---------------------------------------------------------------------------
__global__ __launch_bounds__(256) void lstm_step(
    const float* __restrict__ G, const float* __restrict__ Whh,
    float* __restrict__ hbuf, float* __restrict__ cbuf,
    float* __restrict__ sc, int sl, int s_glob, int p_in)
{
    __shared__ __align__(16) float Hs[4 * 64 * 32];   // 32 KB, also psum alias
    __shared__ __align__(16) float Ws[4 * 64 * 32];   // 32 KB

    const int t    = threadIdx.x;
    const int w    = t >> 6;
    const int lane = t & 63;
    const int rnn  = blockIdx.x >> 3;
    const int b0   = (blockIdx.x * 32) & 255;
    const int J0   = blockIdx.y * 8;

    const float* hprev = hbuf + (size_t)(rnn * 2 + p_in) * (B_ * H_);

    {
        const int row = lane >> 1;
        const int kin = (lane & 1) * 32;
        const int kh  = w * 64 + kin;
        const float* hsrc = hprev + (size_t)(b0 + row) * H_ + kh;
        const int wrow = (row >> 3) * H_ + J0 + (row & 7);
        const float* wsrc = Whh + (size_t)wrow * H_ + kh;
        float* hd = &Hs[w * (64 * 32)];
        float* wd = &Ws[w * (64 * 32)];
        #pragma unroll
        for (int i = 0; i < 8; ++i) {
            const float4 hv = *(const float4*)(hsrc + 4 * i);
            const float4 wv = *(const float4*)(wsrc + 4 * i);
            const int kb = kin + 4 * i;
            hd[(kb + 0) * 32 + row] = hv.x;
            hd[(kb + 1) * 32 + row] = hv.y;
            hd[(kb + 2) * 32 + row] = hv.z;
            hd[(kb + 3) * 32 + row] = hv.w;
            wd[(kb + 0) * 32 + row] = wv.x;
            wd[(kb + 1) * 32 + row] = wv.y;
            wd[(kb + 2) * 32 + row] = wv.z;
            wd[(kb + 3) * 32 + row] = wv.w;
        }
    }
    __syncthreads();

    const int ty = lane >> 3;
    const int tx = lane & 7;
    float acc[4][4];
    #pragma unroll
    for (int i = 0; i < 4; ++i)
        #pragma unroll
        for (int j = 0; j < 4; ++j) acc[i][j] = 0.0f;

    const float* hS = &Hs[w * (64 * 32)];
    const float* wS = &Ws[w * (64 * 32)];
    #pragma unroll 8
    for (int kk = 0; kk < 64; ++kk) {
        const float4 a = *(const float4*)&hS[kk * 32 + 4 * ty];
        const float4 v = *(const float4*)&wS[kk * 32 + 4 * tx];
        const float av[4] = {a.x, a.y, a.z, a.w};
        const float vv[4] = {v.x, v.y, v.z, v.w};
        #pragma unroll
        for (int i = 0; i < 4; ++i)
            #pragma unroll
            for (int j = 0; j < 4; ++j)
                acc[i][j] = fmaf(av[i], vv[j], acc[i][j]);
    }
    __syncthreads();

    float* ps = Hs;
    #pragma unroll
    for (int i = 0; i < 4; ++i)
        #pragma unroll
        for (int j = 0; j < 4; ++j)
            ps[w * (32 * 33) + (4 * ty + i) * 33 + (4 * tx + j)] = acc[i][j];
    __syncthreads();

    const int bl = t >> 3;
    const int jj = t & 7;
    const int b  = b0 + bl;
    const int j  = J0 + jj;
    float g4[4];
    #pragma unroll
    for (int gt = 0; gt < 4; ++gt) {
        const int c0 = bl * 33 + gt * 8 + jj;
        g4[gt] = ps[c0] + ps[1056 + c0] + ps[2112 + c0] + ps[3168 + c0];
    }
    const float* Gr = G + ((size_t)(rnn * CH + sl) * B_ + b) * G4H + j;
    const float gi = g4[0] + Gr[0];
    const float gf = g4[1] + Gr[H_];
    const float gg = g4[2] + Gr[2 * H_];
    const float go = g4[3] + Gr[3 * H_];
    const int ci = rnn * (B_ * H_) + b * H_ + j;
    const float c = sigf(gf) * cbuf[ci] + sigf(gi) * tanhf(gg);
    const float h = sigf(go) * tanhf(c);
    cbuf[ci] = c;
    hbuf[(size_t)(rnn * 2 + (1 - p_in)) * (B_ * H_) + b * H_ + j] = h;
    if (rnn == 0) sc[((size_t)b * S_ + s_glob) * H_ + j] = h;
}

// ---------------------------------------------------------------------------
// Fused attention epilogue, one block per batch row b.
// ---------------------------------------------------------------------------
__global__ __launch_bounds__(256) void final_kernel(
    const float* __restrict__ sc, const float* __restrict__ r,
    const float* __restrict__ Wattn, const float* __restrict__ battn,
    const float* __restrict__ M, const float* __restrict__ bscal,
    const float* __restrict__ mask, float* __restrict__ out)
{
    __shared__ float rs[256], us[256], red[256], as_[256];
    const int b = blockIdx.x;
    const int t = threadIdx.x;

    rs[t] = r[b * 256 + t];
    __syncthreads();

    float acc = 0.0f;
    for (int h = 0; h < 256; ++h) acc += rs[h] * Wattn[h * 256 + t];
    us[t] = acc;

    red[t] = battn[t] * rs[t];
    __syncthreads();
    for (int off = 128; off; off >>= 1) {
        if (t < off) red[t] += red[t + off];
        __syncthreads();
    }
    float beta = red[0];
    __syncthreads();

    float vh = 0.0f;
    {
        const float* Mrow = M + t * 256;
        for (int k = 0; k < 256; ++k) vh += Mrow[k] * rs[k];
    }

    float e = -INFINITY;
    if (t < S_) {
        float d = 0.0f;
        const float* scrow = sc + ((size_t)b * S_ + t) * H_;
        for (int h = 0; h < 256; ++h) d += scrow[h] * us[h];
        e = (d + beta) * mask[b * S_ + t];
    }
    red[t] = e;
    __syncthreads();
    for (int off = 128; off; off >>= 1) {
        if (t < off) red[t] = fmaxf(red[t], red[t + off]);
        __syncthreads();
    }
    float mx = red[0];
    __syncthreads();

    float p = (t < S_) ? expf(e - mx) : 0.0f;
    as_[t] = p;
    red[t] = p;
    __syncthreads();
    for (int off = 128; off; off >>= 1) {
        if (t < off) red[t] += red[t + off];
        __syncthreads();
    }
    float inv = 1.0f / red[0];
    __syncthreads();

    float ca = 0.0f;
    for (int s = 0; s < S_; ++s) ca += as_[s] * sc[((size_t)b * S_ + s) * H_ + t];
    ca *= inv;

    red[t] = ca * vh;
    __syncthreads();
    for (int off = 128; off; off >>= 1) {
        if (t < off) red[t] += red[t + off];
        __syncthreads();
    }
    if (t == 0) out[b] = red[0] + bscal[0];
}

// ---------------------------------------------------------------------------
extern "C" void kernel_launch(void* const* d_in, const int* in_sizes, int n_in,
                              void* d_out, int out_size, void* d_ws, size_t ws_size,
                              hipStream_t stream)
{
    const int*   x1    = (const int*)d_in[0];
    const int*   x2    = (const int*)d_in[1];
    const float* mask  = (const float*)d_in[2];
    const float* key_c = (const float*)d_in[3];
    const float* key_r = (const float*)d_in[4];
    const float* emb   = (const float*)d_in[5];
    const float* Wih   = (const float*)d_in[6];
    const float* Whh   = (const float*)d_in[7];
    const float* Wkh   = (const float*)d_in[8];
    const float* bg    = (const float*)d_in[9];
    const float* Wattn = (const float*)d_in[10];
    const float* battn = (const float*)d_in[11];
    const float* M     = (const float*)d_in[12];
    const float* bb    = (const float*)d_in[13];
    float* out = (float*)d_out;
    float* ws  = (float*)d_ws;

    const size_t off_sc = 0;
    const size_t off_G  = off_sc + (size_t)B_ * S_ * H_;        // 10,485,760
    const size_t off_h  = off_G + (size_t)2 * CH * B_ * G4H;    // +8,388,608
    const size_t off_c  = off_h + (size_t)4 * B_ * H_;
    const size_t total  = off_c + (size_t)2 * B_ * H_;
    if (ws_size < total * sizeof(float)) return;  // workspace too small: fail visibly

    float* sc   = ws + off_sc;
    float* G    = ws + off_G;
    float* hbuf = ws + off_h;
    float* cbuf = ws + off_c;

    // zero h (both parities, both RNNs) and c
    hipMemsetAsync(hbuf, 0, (size_t)(6 * B_ * H_) * sizeof(float), stream);

    for (int ci = 0; ci < NCH; ++ci) {
        gemm_g2<<<dim3(32, 8, 2), 256, 0, stream>>>(x1, x2, key_c, key_r, emb,
                                                    Wih, Wkh, bg, G, ci * CH);
        for (int slq = 0; slq < CH; ++slq) {
            int tstep = ci * CH + slq;
            lstm_step<<<dim3(16, 32), 256, 0, stream>>>(G, Whh, hbuf, cbuf, sc,
                                                        slq, tstep, tstep & 1);
        }
    }

    const float* rfin = hbuf + (size_t)(1 * 2 + 0) * (B_ * H_);
    final_kernel<<<dim3(256), 256, 0, stream>>>(sc, rfin, Wattn, battn, M, bb, mask, out);
}

// Round 4
// 1760.537 us; speedup vs baseline: 2.7985x; 1.1489x over previous
//
#include <hip/hip_runtime.h>
#include <math.h>

#define B_   256
#define S_   160
#define E_   300
#define H_   256
#define T_   200
#define G4H  1024
#define CH   16
#define NCH  10

typedef float  f32x4  __attribute__((ext_vector_type(4)));
typedef __bf16 bf16x4 __attribute__((ext_vector_type(4)));
typedef __bf16 bf16x8 __attribute__((ext_vector_type(8)));

__device__ __forceinline__ float sigf(float x) {
    float e = expf(-fabsf(x));
    float p = 1.0f / (1.0f + e);
    return x >= 0.0f ? p : e * p;
}

// 4 consecutive K-values from concatenated [first(300) | second(200) | pad] row
__device__ __forceinline__ float4 pick4(const float* __restrict__ e,
                                        const float* __restrict__ k, int kg) {
    if (kg < E_)      return *(const float4*)(e + kg);
    if (kg < E_ + T_) return *(const float4*)(k + (kg - E_));
    return make_float4(0.f, 0.f, 0.f, 0.f);
}

__device__ __forceinline__ void split4(float4 v, bf16x4& h, bf16x4& l) {
    h[0] = (__bf16)v.x; l[0] = (__bf16)(v.x - (float)h[0]);
    h[1] = (__bf16)v.y; l[1] = (__bf16)(v.y - (float)h[1]);
    h[2] = (__bf16)v.z; l[2] = (__bf16)(v.z - (float)h[2]);
    h[3] = (__bf16)v.w; l[3] = (__bf16)(v.w - (float)h[3]);
}

// ---------------------------------------------------------------------------
// Input GEMM (unchanged from round 3): split-bf16 MFMA, tile 128x128, BK=32.
// ---------------------------------------------------------------------------
__global__ __launch_bounds__(256, 2) void gemm_g2(
    const int* __restrict__ x1, const int* __restrict__ x2,
    const float* __restrict__ key_c, const float* __restrict__ key_r,
    const float* __restrict__ emb, const float* __restrict__ Wih,
    const float* __restrict__ Wkh, const float* __restrict__ bg,
    float* __restrict__ G, int s0)
{
    __shared__ __align__(16) __bf16 Ah[128 * 32];
    __shared__ __align__(16) __bf16 Al[128 * 32];
    __shared__ __align__(16) __bf16 Bh[128 * 32];
    __shared__ __align__(16) __bf16 Bl[128 * 32];

    const int t   = threadIdx.x;
    const int rnn = blockIdx.z;
    const int m0  = blockIdx.x * 128;
    const int n0  = blockIdx.y * 128;
    const int* xx = rnn ? x2 : x1;
    const float* key = rnn ? key_r : key_c;

    const int r0  = t >> 3;
    const int kq  = t & 7;
    const int csw = (((kq >> 1) ^ ((r0 >> 1) & 3)) * 16) + (kq & 1) * 8;

    const float* aeb[4]; const float* akb[4];
    const float* wv1[4]; const float* wv2[4];
    #pragma unroll
    for (int i = 0; i < 4; ++i) {
        const int row = r0 + 32 * i;
        const int am  = m0 + row;
        const int bs  = (am >> 4) * S_ + s0 + (am & 15);
        aeb[i] = emb + (size_t)xx[bs] * E_;
        akb[i] = key + (size_t)bs * T_;
        const int n = n0 + row;
        wv1[i] = Wih + (size_t)n * E_;
        wv2[i] = Wkh + (size_t)n * T_;
    }

    const int w  = t >> 6;
    const int wm = w >> 1;
    const int wn = w & 1;
    const int l  = t & 63;
    const int cl = l & 15;
    const int ch = l >> 4;
    const int chs = ((ch ^ ((cl >> 1) & 3)) * 16);

    f32x4 acc[4][4];
    #pragma unroll
    for (int fm = 0; fm < 4; ++fm)
        #pragma unroll
        for (int fn = 0; fn < 4; ++fn) acc[fm][fn] = (f32x4){0.f, 0.f, 0.f, 0.f};

    for (int kt = 0; kt < 16; ++kt) {
        const int kg = kt * 32 + kq * 4;
        bf16x4 sAh[4], sAl[4], sBh[4], sBl[4];
        #pragma unroll
        for (int i = 0; i < 4; ++i) {
            const float4 va = pick4(aeb[i], akb[i], kg);
            const float4 vb = pick4(wv1[i], wv2[i], kg);
            split4(va, sAh[i], sAl[i]);
            split4(vb, sBh[i], sBl[i]);
        }
        __syncthreads();
        #pragma unroll
        for (int i = 0; i < 4; ++i) {
            const int off = (r0 + 32 * i) * 64 + csw;
            *(bf16x4*)((char*)Ah + off) = sAh[i];
            *(bf16x4*)((char*)Al + off) = sAl[i];
            *(bf16x4*)((char*)Bh + off) = sBh[i];
            *(bf16x4*)((char*)Bl + off) = sBl[i];
        }
        __syncthreads();

        bf16x8 fBh[4], fBl[4];
        #pragma unroll
        for (int fn = 0; fn < 4; ++fn) {
            const int off = (wn * 64 + fn * 16 + cl) * 64 + chs;
            fBh[fn] = *(const bf16x8*)((const char*)Bh + off);
            fBl[fn] = *(const bf16x8*)((const char*)Bl + off);
        }
        #pragma unroll
        for (int fm = 0; fm < 4; ++fm) {
            const int off = (wm * 64 + fm * 16 + cl) * 64 + chs;
            const bf16x8 fAh = *(const bf16x8*)((const char*)Ah + off);
            const bf16x8 fAl = *(const bf16x8*)((const char*)Al + off);
            #pragma unroll
            for (int fn = 0; fn < 4; ++fn) {
                acc[fm][fn] = __builtin_amdgcn_mfma_f32_16x16x32_bf16(fAh, fBh[fn], acc[fm][fn], 0, 0, 0);
                acc[fm][fn] = __builtin_amdgcn_mfma_f32_16x16x32_bf16(fAh, fBl[fn], acc[fm][fn], 0, 0, 0);
                acc[fm][fn] = __builtin_amdgcn_mfma_f32_16x16x32_bf16(fAl, fBh[fn], acc[fm][fn], 0, 0, 0);
            }
        }
    }

    float bgl[4];
    #pragma unroll
    for (int fn = 0; fn < 4; ++fn) bgl[fn] = bg[n0 + wn * 64 + fn * 16 + cl];

    #pragma unroll
    for (int fm = 0; fm < 4; ++fm) {
        #pragma unroll
        for (int r = 0; r < 4; ++r) {
            const int m  = m0 + wm * 64 + fm * 16 + ch * 4 + r;
            const int b  = m >> 4;
            const int sl = m & 15;
            float* rowp = G + ((size_t)(rnn * CH + sl) * B_ + b) * G4H;
            #pragma unroll
            for (int fn = 0; fn < 4; ++fn)
                rowp[n0 + wn * 64 + fn * 16 + cl] = acc[fm][fn][r] + bgl[fn];
        }
    }
}

// ---------------------------------------------------------------------------
// Split Whh (1024x256 fp32) into bf16 hi/lo planes. 256 blocks x 256 thr x 4.
// ---------------------------------------------------------------------------
__global__ __launch_bounds__(256) void whh_split(
    const float* __restrict__ W, __bf16* __restrict__ hi, __bf16* __restrict__ lo)
{
    const int i4 = (blockIdx.x * 256 + threadIdx.x) * 4;
    const float4 v = *(const float4*)(W + i4);
    bf16x4 h, l;
    split4(v, h, l);
    *(bf16x4*)(hi + i4) = h;
    *(bf16x4*)(lo + i4) = l;
}

// ---------------------------------------------------------------------------
// One LSTM step via split-bf16 MFMA. Grid (16 mg, 8 ng) = 128 blocks, 256 thr.
// Tile: 32 rows (m = rnn*256+b) x 128 cols = 4 gates x 32 j's (j = j0+0..31);
// wave w owns gate w (rows w*32..w*32+31 of the B tile). K=256, 2 phases of
// 128. LDS: Bh|Bl|Ah|Al (80KB) with gemm_g2's XOR-chunk swizzle; gs (fp32
// [32][132]) aliases the base for the cross-wave gate transpose. Epilogue:
// gates += G, nonlinearity, c update, h hi/lo + sc writes.
// ---------------------------------------------------------------------------
__global__ __launch_bounds__(256) void lstm_mfma(
    const float* __restrict__ G,
    const __bf16* __restrict__ Whi, const __bf16* __restrict__ Wlo,
    const __bf16* __restrict__ hhi_in, const __bf16* __restrict__ hlo_in,
    __bf16* __restrict__ hhi_out, __bf16* __restrict__ hlo_out,
    float* __restrict__ cst, float* __restrict__ sc,
    int sl, int s_glob)
{
    __shared__ __align__(16) char smem[81920];
    __bf16* Bh = (__bf16*)smem;                 // [4 ksub][128 rows][64B]
    __bf16* Bl = (__bf16*)(smem + 32768);
    __bf16* Ah = (__bf16*)(smem + 65536);       // [4 ksub][32 rows][64B]
    __bf16* Al = (__bf16*)(smem + 73728);
    float*  gs = (float*)smem;                  // [32][132] alias

    const int t   = threadIdx.x;
    const int mg  = blockIdx.x;       // 0..15
    const int ng  = blockIdx.y;       // 0..7
    const int m0  = mg * 32;
    const int j0  = ng * 32;
    const int rnn = mg >> 3;

    // staging mapping
    const int r0  = t >> 3;           // 0..31
    const int kq  = t & 7;            // 0..7
    const int csw = (((kq >> 1) ^ ((r0 >> 1) & 3)) * 16) + (kq & 1) * 8;

    const __bf16* Asrc_h = hhi_in + (size_t)(m0 + r0) * 256;
    const __bf16* Asrc_l = hlo_in + (size_t)(m0 + r0) * 256;

    // compute mapping
    const int w  = t >> 6;            // gate id
    const int l  = t & 63;
    const int cl = l & 15;
    const int ch = l >> 4;
    const int sw = (ch ^ ((cl >> 1) & 3)) * 16;

    f32x4 acc[2][2];
    #pragma unroll
    for (int fm = 0; fm < 2; ++fm)
        #pragma unroll
        for (int fn = 0; fn < 2; ++fn) acc[fm][fn] = (f32x4){0.f, 0.f, 0.f, 0.f};

    bf16x4 a_h[4], a_l[4], b_h[4][4], b_l[4][4];

#define LOAD_PHASE(p)                                                          \
    {                                                                          \
        _Pragma("unroll")                                                      \
        for (int ks = 0; ks < 4; ++ks) {                                       \
            const int k = (p) * 128 + ks * 32 + kq * 4;                        \
            a_h[ks] = *(const bf16x4*)(Asrc_h + k);                            \
            a_l[ks] = *(const bf16x4*)(Asrc_l + k);                            \
            _Pragma("unroll")                                                  \
            for (int i = 0; i < 4; ++i) {                                      \
                const size_t off = (size_t)(i * 256 + j0 + r0) * 256 + k;      \
                b_h[i][ks] = *(const bf16x4*)(Whi + off);                      \
                b_l[i][ks] = *(const bf16x4*)(Wlo + off);                      \
            }                                                                  \
        }                                                                      \
    }

#define STORE_PHASE()                                                          \
    {                                                                          \
        _Pragma("unroll")                                                      \
        for (int ks = 0; ks < 4; ++ks) {                                       \
            *(bf16x4*)((char*)Ah + ks * 2048 + r0 * 64 + csw) = a_h[ks];       \
            *(bf16x4*)((char*)Al + ks * 2048 + r0 * 64 + csw) = a_l[ks];       \
            _Pragma("unroll")                                                  \
            for (int i = 0; i < 4; ++i) {                                      \
                const int rr = i * 32 + r0;                                    \
                *(bf16x4*)((char*)Bh + ks * 8192 + rr * 64 + csw) = b_h[i][ks];\
                *(bf16x4*)((char*)Bl + ks * 8192 + rr * 64 + csw) = b_l[i][ks];\
            }                                                                  \
        }                                                                      \
    }

#define MFMA_PHASE()                                                           \
    {                                                                          \
        _Pragma("unroll")                                                      \
        for (int ks = 0; ks < 4; ++ks) {                                       \
            bf16x8 fAh[2], fAl[2], fBh[2], fBl[2];                             \
            _Pragma("unroll")                                                  \
            for (int f = 0; f < 2; ++f) {                                      \
                const int ao = ks * 2048 + (f * 16 + cl) * 64 + sw;            \
                fAh[f] = *(const bf16x8*)((const char*)Ah + ao);               \
                fAl[f] = *(const bf16x8*)((const char*)Al + ao);               \
                const int bo = ks * 8192 + (w * 32 + f * 16 + cl) * 64 + sw;   \
                fBh[f] = *(const bf16x8*)((const char*)Bh + bo);               \
                fBl[f] = *(const bf16x8*)((const char*)Bl + bo);               \
            }                                                                  \
            _Pragma("unroll")                                                  \
            for (int fm = 0; fm < 2; ++fm)                                     \
                _Pragma("unroll")                                              \
                for (int fn = 0; fn < 2; ++fn) {                               \
                    acc[fm][fn] = __builtin_amdgcn_mfma_f32_16x16x32_bf16(     \
                        fAh[fm], fBh[fn], acc[fm][fn], 0, 0, 0);               \
                    acc[fm][fn] = __builtin_amdgcn_mfma_f32_16x16x32_bf16(     \
                        fAh[fm], fBl[fn], acc[fm][fn], 0, 0, 0);               \
                    acc[fm][fn] = __builtin_amdgcn_mfma_f32_16x16x32_bf16(     \
                        fAl[fm], fBh[fn], acc[fm][fn], 0, 0, 0);               \
                }                                                              \
        }                                                                      \
    }

    LOAD_PHASE(0);
    STORE_PHASE();
    __syncthreads();
    LOAD_PHASE(1);        // issue phase-1 global loads under phase-0 MFMA
    MFMA_PHASE();
    __syncthreads();
    STORE_PHASE();
    __syncthreads();
    MFMA_PHASE();
    __syncthreads();      // all LDS reads done; gs alias is now safe

    // cross-wave gate transpose: gs[m][gate*32 + jj]
    #pragma unroll
    for (int fm = 0; fm < 2; ++fm)
        #pragma unroll
        for (int fn = 0; fn < 2; ++fn)
            #pragma unroll
            for (int r = 0; r < 4; ++r)
                gs[(fm * 16 + ch * 4 + r) * 132 + (w * 32 + fn * 16 + cl)] = acc[fm][fn][r];
    __syncthreads();

    // gate math: thread -> (m = t>>3, 4 j's)
    const int m   = t >> 3;
    const int jj4 = (t & 7) * 4;
    const int gm  = m0 + m;
    const int b   = gm & 255;

    const float4 vi = *(const float4*)&gs[m * 132 + 0  + jj4];
    const float4 vf = *(const float4*)&gs[m * 132 + 32 + jj4];
    const float4 vg = *(const float4*)&gs[m * 132 + 64 + jj4];
    const float4 vo = *(const float4*)&gs[m * 132 + 96 + jj4];

    const float* Gb = G + ((size_t)(rnn * CH + sl) * B_ + b) * G4H + j0 + jj4;
    const float4 Gi = *(const float4*)(Gb);
    const float4 Gf = *(const float4*)(Gb + 256);
    const float4 Gg = *(const float4*)(Gb + 512);
    const float4 Go = *(const float4*)(Gb + 768);

    float* cp = cst + (size_t)gm * 256 + j0 + jj4;
    float4 cv = *(const float4*)cp;

    const float gi4[4] = {vi.x + Gi.x, vi.y + Gi.y, vi.z + Gi.z, vi.w + Gi.w};
    const float gf4[4] = {vf.x + Gf.x, vf.y + Gf.y, vf.z + Gf.z, vf.w + Gf.w};
    const float gg4[4] = {vg.x + Gg.x, vg.y + Gg.y, vg.z + Gg.z, vg.w + Gg.w};
    const float go4[4] = {vo.x + Go.x, vo.y + Go.y, vo.z + Go.z, vo.w + Go.w};
    float cc[4] = {cv.x, cv.y, cv.z, cv.w};

    float hv[4];
    bf16x4 h_hi, h_lo;
    #pragma unroll
    for (int q = 0; q < 4; ++q) {
        const float c = sigf(gf4[q]) * cc[q] + sigf(gi4[q]) * tanhf(gg4[q]);
        const float h = sigf(go4[q]) * tanhf(c);
        cc[q] = c;
        hv[q] = h;
        h_hi[q] = (__bf16)h;
        h_lo[q] = (__bf16)(h - (float)h_hi[q]);
    }
    *(float4*)cp = make_float4(cc[0], cc[1], cc[2], cc[3]);
    *(bf16x4*)(hhi_out + (size_t)gm * 256 + j0 + jj4) = h_hi;
    *(bf16x4*)(hlo_out + (size_t)gm * 256 + j0 + jj4) = h_lo;
    if (rnn == 0)
        *(float4*)(sc + ((size_t)b * S_ + s_glob) * H_ + j0 + jj4) =
            make_float4(hv[0], hv[1], hv[2], hv[3]);
}

// ---------------------------------------------------------------------------
// Fused attention epilogue, one block per batch row b. r reconstructed from
// the rnn1 parity-0 h hi/lo planes.
// ---------------------------------------------------------------------------
__global__ __launch_bounds__(256) void final_kernel(
    const float* __restrict__ sc,
    const __bf16* __restrict__ rhi, const __bf16* __restrict__ rlo,
    const float* __restrict__ Wattn, const float* __restrict__ battn,
    const float* __restrict__ M, const float* __restrict__ bscal,
    const float* __restrict__ mask, float* __restrict__ out)
{
    __shared__ float rs[256], us[256], red[256], as_[256];
    const int b = blockIdx.x;
    const int t = threadIdx.x;

    const size_t ri = (size_t)(256 + b) * 256 + t;
    rs[t] = (float)rhi[ri] + (float)rlo[ri];
    __syncthreads();

    float acc = 0.0f;
    for (int h = 0; h < 256; ++h) acc += rs[h] * Wattn[h * 256 + t];
    us[t] = acc;

    red[t] = battn[t] * rs[t];
    __syncthreads();
    for (int off = 128; off; off >>= 1) {
        if (t < off) red[t] += red[t + off];
        __syncthreads();
    }
    float beta = red[0];
    __syncthreads();

    float vh = 0.0f;
    {
        const float* Mrow = M + t * 256;
        for (int k = 0; k < 256; ++k) vh += Mrow[k] * rs[k];
    }

    float e = -INFINITY;
    if (t < S_) {
        float d = 0.0f;
        const float* scrow = sc + ((size_t)b * S_ + t) * H_;
        for (int h = 0; h < 256; ++h) d += scrow[h] * us[h];
        e = (d + beta) * mask[b * S_ + t];
    }
    red[t] = e;
    __syncthreads();
    for (int off = 128; off; off >>= 1) {
        if (t < off) red[t] = fmaxf(red[t], red[t + off]);
        __syncthreads();
    }
    float mx = red[0];
    __syncthreads();

    float p = (t < S_) ? expf(e - mx) : 0.0f;
    as_[t] = p;
    red[t] = p;
    __syncthreads();
    for (int off = 128; off; off >>= 1) {
        if (t < off) red[t] += red[t + off];
        __syncthreads();
    }
    float inv = 1.0f / red[0];
    __syncthreads();

    float ca = 0.0f;
    for (int s = 0; s < S_; ++s) ca += as_[s] * sc[((size_t)b * S_ + s) * H_ + t];
    ca *= inv;

    red[t] = ca * vh;
    __syncthreads();
    for (int off = 128; off; off >>= 1) {
        if (t < off) red[t] += red[t + off];
        __syncthreads();
    }
    if (t == 0) out[b] = red[0] + bscal[0];
}

// ---------------------------------------------------------------------------
extern "C" void kernel_launch(void* const* d_in, const int* in_sizes, int n_in,
                              void* d_out, int out_size, void* d_ws, size_t ws_size,
                              hipStream_t stream)
{
    const int*   x1    = (const int*)d_in[0];
    const int*   x2    = (const int*)d_in[1];
    const float* mask  = (const float*)d_in[2];
    const float* key_c = (const float*)d_in[3];
    const float* key_r = (const float*)d_in[4];
    const float* emb   = (const float*)d_in[5];
    const float* Wih   = (const float*)d_in[6];
    const float* Whh   = (const float*)d_in[7];
    const float* Wkh   = (const float*)d_in[8];
    const float* bg    = (const float*)d_in[9];
    const float* Wattn = (const float*)d_in[10];
    const float* battn = (const float*)d_in[11];
    const float* M     = (const float*)d_in[12];
    const float* bb    = (const float*)d_in[13];
    float* out = (float*)d_out;
    char*  wsb = (char*)d_ws;

    // byte layout
    float*  G    = (float*)(wsb + 0);            // 33,554,432 B
    float*  sc   = (float*)(wsb + 33554432);     // 41,943,040 B
    float*  cst  = (float*)(wsb + 75497472);     //    524,288 B
    __bf16* hhi0 = (__bf16*)(wsb + 76021760);    //    262,144 B
    __bf16* hlo0 = (__bf16*)(wsb + 76283904);
    __bf16* hhi1 = (__bf16*)(wsb + 76546048);
    __bf16* hlo1 = (__bf16*)(wsb + 76808192);
    __bf16* Whi  = (__bf16*)(wsb + 77070336);    //    524,288 B
    __bf16* Wlo  = (__bf16*)(wsb + 77594624);
    if (ws_size < 78118912) return;  // fail visibly if workspace too small

    // zero c + parity-0 h planes (contiguous 1 MB)
    hipMemsetAsync(wsb + 75497472, 0, 1048576, stream);
    whh_split<<<dim3(256), 256, 0, stream>>>(Whh, Whi, Wlo);

    int cur = 0;
    for (int ci = 0; ci < NCH; ++ci) {
        gemm_g2<<<dim3(32, 8, 2), 256, 0, stream>>>(x1, x2, key_c, key_r, emb,
                                                    Wih, Wkh, bg, G, ci * CH);
        for (int slq = 0; slq < CH; ++slq) {
            const int tstep = ci * CH + slq;
            __bf16* hi_in  = cur ? hhi1 : hhi0;
            __bf16* lo_in  = cur ? hlo1 : hlo0;
            __bf16* hi_out = cur ? hhi0 : hhi1;
            __bf16* lo_out = cur ? hlo0 : hlo1;
            lstm_mfma<<<dim3(16, 8), 256, 0, stream>>>(G, Whi, Wlo,
                                                       hi_in, lo_in, hi_out, lo_out,
                                                       cst, sc, slq, tstep);
            cur ^= 1;
        }
    }

    // after 160 steps the last write parity is buffer 0; r = rnn1 rows
    final_kernel<<<dim3(256), 256, 0, stream>>>(sc, hhi0, hlo0, Wattn, battn,
                                                M, bb, mask, out);
}